// Round 12
// baseline (185.766 us; speedup 1.0000x reference)
//
#include <hip/hip_runtime.h>
#include <hip/hip_bf16.h>
#include <cstdint>
#include <cstddef>

// Problem shape (fixed): x [B=16][N=2048][D=512] fp32
#define BB 16
#define NN 2048
#define DD 512

typedef _Float16 f16x8 __attribute__((ext_vector_type(8)));
typedef _Float16 f16x4 __attribute__((ext_vector_type(4)));
typedef float f32x4 __attribute__((ext_vector_type(4)));
typedef unsigned int u32x4 __attribute__((ext_vector_type(4)));

// Async global->LDS, 16 B per lane. LDS dest = wave-uniform base + lane*16.
__device__ __forceinline__ void async_ld16(void* lds, const void* g) {
    __builtin_amdgcn_global_load_lds(
        (const __attribute__((address_space(1))) unsigned int*)(uintptr_t)g,
        (__attribute__((address_space(3))) unsigned int*)(uint32_t)(uintptr_t)lds,
        16, 0, 0);
}

#define VM_WAIT(n) asm volatile("s_waitcnt vmcnt(" #n ")" ::: "memory")
#define RAW_BAR()  do { asm volatile("" ::: "memory"); __builtin_amdgcn_s_barrier(); asm volatile("" ::: "memory"); } while (0)
// LDS-order-only barrier: global stores/atomics keep draining.
#define LGKM_BAR() do { asm volatile("s_waitcnt lgkmcnt(0)" ::: "memory"); \
                        __builtin_amdgcn_s_barrier();                      \
                        __builtin_amdgcn_sched_barrier(0); } while (0)
// Wait own ds_reads, then fence the scheduler (rule #18: MFMA must not hoist).
#define LGKM0_FENCE() do { asm volatile("s_waitcnt lgkmcnt(0)" ::: "memory"); \
                           __builtin_amdgcn_sched_barrier(0); } while (0)

// ---------------------------------------------------------------------------
// K1 (fused): read x ONCE (non-temporal: stream-once). Per 64-row slab:
// norms, xhn (normalized fp16), vT (fp16 transpose), denom zero-init.
// grid (NN/64, BB), 256 threads.
// ---------------------------------------------------------------------------
__global__ __launch_bounds__(256) void k_prep(const float* __restrict__ x,
                                              _Float16* __restrict__ xhn,
                                              _Float16* __restrict__ vT,
                                              float* __restrict__ denom) {
    __shared__ _Float16 t[512 * 66];     // [d][j], pitch 66 halves
    const int tid = threadIdx.x, lane = tid & 63, w = tid >> 6;
    const int b = blockIdx.y, j0 = blockIdx.x * 64;
    if (tid < 64) denom[b * NN + j0 + tid] = 0.f;
    const float* xb = x + ((size_t)b * NN + j0) * DD;

    for (int rr = 0; rr < 16; ++rr) {
        const int jj = w * 16 + rr;                 // row within slab
        const float* xr = xb + (size_t)jj * DD;
        f32x4 a = __builtin_nontemporal_load((const f32x4*)xr + lane);
        f32x4 c = __builtin_nontemporal_load((const f32x4*)xr + lane + 64);
        float ss = a[0]*a[0] + a[1]*a[1] + a[2]*a[2] + a[3]*a[3]
                 + c[0]*c[0] + c[1]*c[1] + c[2]*c[2] + c[3]*c[3];
        #pragma unroll
        for (int o = 1; o < 64; o <<= 1) ss += __shfl_xor(ss, o);
        const float rn = 1.0f / sqrtf(ss);
        // normalized fp16 row (coalesced 8B stores)
        _Float16* dst = xhn + ((size_t)b * NN + j0 + jj) * DD;
        f16x4 v0 = {(_Float16)(a[0]*rn), (_Float16)(a[1]*rn), (_Float16)(a[2]*rn), (_Float16)(a[3]*rn)};
        f16x4 v1 = {(_Float16)(c[0]*rn), (_Float16)(c[1]*rn), (_Float16)(c[2]*rn), (_Float16)(c[3]*rn)};
        *(f16x4*)(dst + 4 * lane) = v0;
        *(f16x4*)(dst + 256 + 4 * lane) = v1;
        // unnormalized fp16 into transposed LDS tile
        const int d0 = 4 * lane, d1 = 256 + 4 * lane;
        t[(d0 + 0) * 66 + jj] = (_Float16)a[0];
        t[(d0 + 1) * 66 + jj] = (_Float16)a[1];
        t[(d0 + 2) * 66 + jj] = (_Float16)a[2];
        t[(d0 + 3) * 66 + jj] = (_Float16)a[3];
        t[(d1 + 0) * 66 + jj] = (_Float16)c[0];
        t[(d1 + 1) * 66 + jj] = (_Float16)c[1];
        t[(d1 + 2) * 66 + jj] = (_Float16)c[2];
        t[(d1 + 3) * 66 + jj] = (_Float16)c[3];
    }
    LGKM_BAR();   // xhn global stores keep draining under the vT phase
    // store vT rows: 512 d x 8 chunks of 8 halves; 4B-aligned b32 LDS reads.
    #pragma unroll
    for (int it = 0; it < 16; ++it) {
        const int id = it * 256 + tid;
        const int d = id >> 3, ch = (id & 7) * 8;
        const uint32_t* tp = (const uint32_t*)&t[d * 66 + ch];
        uint4 v = {tp[0], tp[1], tp[2], tp[3]};
        *(uint4*)(vT + ((size_t)b * DD + d) * NN + j0 + ch) = v;
    }
}

// ---------------------------------------------------------------------------
// K2 (unchanged from R11, measured ~78 us): W = exp( xhn xhn^T ),
// symmetric-triangular. 128x128 block, 4 waves, single-buffered BK=64,
// 34 KiB LDS -> 4 blocks/CU, XCD tile-pair swizzle, lane-coalesced stores.
// ---------------------------------------------------------------------------
__global__ __launch_bounds__(256, 4) void k_scores(const _Float16* __restrict__ xhn,
                                                   _Float16* __restrict__ W,
                                                   float* __restrict__ denom) {
    __shared__ _Float16 smem[17408];          // As[8192]+Bs[8192]; epi: 128x136
    const int tid = threadIdx.x;
    const int lane = tid & 63, wv = tid >> 6;
    const int wr = wv >> 1, wc = wv & 1;
    const int m_ = lane & 15, quad = lane >> 4;
    const int b = blockIdx.z;

    // XCD swizzle: 136 = 8 * 17 -> each XCD gets 17 consecutive pairs.
    const int swz = (blockIdx.x % 8) * 17 + blockIdx.x / 8;
    int rem = swz, ti = 0, rowlen = NN / 128;
    while (rem >= rowlen) { rem -= rowlen; ++ti; --rowlen; }
    const int tj = ti + rem;
    const int I = ti * 128, J = tj * 128;
    const bool diag = (ti == tj);

    const _Float16* Ab = xhn + ((size_t)b * NN + I) * DD;
    const _Float16* Bb = xhn + ((size_t)b * NN + J) * DD;

    f32x4 acc[4][4];
    #pragma unroll
    for (int i = 0; i < 4; ++i)
        #pragma unroll
        for (int j = 0; j < 4; ++j) acc[i][j] = (f32x4){0.f, 0.f, 0.f, 0.f};

    const int sub = lane >> 3;
    const int swc = (lane & 7) ^ sub;
    const _Float16* agl = Ab + (size_t)(wv * 32 + sub) * DD + swc * 8;
    const _Float16* bgl = Bb + (size_t)(wv * 32 + sub) * DD + swc * 8;
    _Float16* As = smem;
    _Float16* Bs = smem + 8192;

    for (int kb = 0; kb < DD / 64; ++kb) {
        const int k0 = kb * 64;
        #pragma unroll
        for (int c = 0; c < 4; ++c) {
            async_ld16(&As[(wv * 32 + c * 8) * 64], agl + (size_t)c * 8 * DD + k0);
            async_ld16(&Bs[(wv * 32 + c * 8) * 64], bgl + (size_t)c * 8 * DD + k0);
        }
        VM_WAIT(0);
        RAW_BAR();
        __builtin_amdgcn_s_setprio(1);
        #pragma unroll
        for (int kc = 0; kc < 2; ++kc) {
            f16x8 af[4], bf[4];
            #pragma unroll
            for (int t = 0; t < 4; ++t) {
                const int Ra = wr * 64 + t * 16 + m_;
                const int Rb = wc * 64 + t * 16 + m_;
                af[t] = *(const f16x8*)&As[Ra * 64 + (((kc * 4 + quad) ^ (Ra & 7)) * 8)];
                bf[t] = *(const f16x8*)&Bs[Rb * 64 + (((kc * 4 + quad) ^ (Rb & 7)) * 8)];
            }
            #pragma unroll
            for (int i = 0; i < 4; ++i)
                #pragma unroll
                for (int j = 0; j < 4; ++j)
                    acc[i][j] = __builtin_amdgcn_mfma_f32_16x16x32_f16(af[i], bf[j], acc[i][j], 0, 0, 0);
        }
        __builtin_amdgcn_s_setprio(0);
        RAW_BAR();   // all waves done reading before next stage overwrites
    }

    // Epilogue: exp into packed f16x4; register row/col sums.
    f16x4 wq[4][4];
    float rowpart[4][4];
    float colpart[4] = {0.f, 0.f, 0.f, 0.f};
    #pragma unroll
    for (int i = 0; i < 4; ++i)
        #pragma unroll
        for (int r = 0; r < 4; ++r) rowpart[i][r] = 0.f;

    #pragma unroll
    for (int i = 0; i < 4; ++i) {
        #pragma unroll
        for (int j = 0; j < 4; ++j) {
            #pragma unroll
            for (int r = 0; r < 4; ++r) {
                const float w = __expf(acc[i][j][r]);
                wq[i][j][r] = (_Float16)w;
                rowpart[i][r] += w;
                colpart[j] += w;
            }
        }
    }

    #pragma unroll
    for (int i = 0; i < 4; ++i) {
        #pragma unroll
        for (int r = 0; r < 4; ++r) {
            float s = rowpart[i][r];
            s += __shfl_xor(s, 1);
            s += __shfl_xor(s, 2);
            s += __shfl_xor(s, 4);
            s += __shfl_xor(s, 8);
            if (m_ == 0)
                atomicAdd(&denom[b * NN + I + wr * 64 + i * 16 + quad * 4 + r], s);
        }
    }
    if (!diag) {
        #pragma unroll
        for (int j = 0; j < 4; ++j) {
            float s = colpart[j];
            s += __shfl_xor(s, 16);
            s += __shfl_xor(s, 32);
            if (quad == 0)
                atomicAdd(&denom[b * NN + J + wc * 64 + j * 16 + m_], s);
        }
    }

    LGKM_BAR();   // LDS ordering only: atomics keep draining

    // Phase 1: WtT[col][row] (stride 136), b64 writes -> coalesced W(J,I).
    _Float16* WtT = smem;
    #pragma unroll
    for (int i = 0; i < 4; ++i) {
        const int rowb = wr * 64 + i * 16 + quad * 4;
        #pragma unroll
        for (int j = 0; j < 4; ++j) {
            const int col = wc * 64 + j * 16 + m_;
            *(f16x4*)&WtT[col * 136 + rowb] = wq[i][j];
        }
    }
    LGKM_BAR();
    // lane-coalesced store: 16 lanes = one contiguous 256 B row segment.
    #pragma unroll
    for (int it2 = 0; it2 < 8; ++it2) {
        const int id = it2 * 256 + tid;
        const int rr = id >> 4, off = (id & 15) * 8;
        *(uint4*)(W + ((size_t)b * NN + J + rr) * NN + I + off) =
            *(const uint4*)&WtT[rr * 136 + off];
    }
    // Phase 2 (off-diag): row-major Wt -> coalesced W(I,J).
    if (!diag) {
        LGKM_BAR();   // phase-1 LDS reads done; W(J,I) stores still in flight
        _Float16* Wt = smem;
        #pragma unroll
        for (int i = 0; i < 4; ++i) {
            const int rowb = wr * 64 + i * 16 + quad * 4;
            #pragma unroll
            for (int j = 0; j < 4; ++j) {
                const int col = wc * 64 + j * 16 + m_;
                #pragma unroll
                for (int r = 0; r < 4; ++r)
                    Wt[(rowb + r) * 136 + col] = wq[i][j][r];
            }
        }
        LGKM_BAR();
        #pragma unroll
        for (int it2 = 0; it2 < 8; ++it2) {
            const int id = it2 * 256 + tid;
            const int rr = id >> 4, off = (id & 15) * 8;
            *(uint4*)(W + ((size_t)b * NN + I + rr) * NN + J + off) =
                *(const uint4*)&Wt[rr * 136 + off];
        }
    }
}

// ---------------------------------------------------------------------------
// K3 REWRITE: m201 8-phase 256x256 template. O = (W @ V) * (1/denom_i).
// 8 waves (2Mx4N, per-wave 128x64 C -> mfma:ds = 64:24 per K-tile), BK=64,
// ring-2 64 KB buffers (132 KB dynamic LDS), per-tile 4 quadrant-phases of
// 16 mfma: {ds cluster -> bar -> lgkm0+sched_bar -> prio1 + 16 MFMA + prio0
// -> bar}. B-frags once per tile; q2 pre-reads q3's A-frags so q3 is
// READ-FREE -> burst-staging tile t+2 into the (now fully-retired) current
// buffer is race-free. vmcnt(8) at tile top; vmcnt(0) last tile only.
// grid flat 256 = 1 block/CU, XCD batch-pinned, d-pairs adjacent.
// ---------------------------------------------------------------------------
__global__ __launch_bounds__(512, 2) void k_pv(const _Float16* __restrict__ W,
                                               const _Float16* __restrict__ vT,
                                               const float* __restrict__ denom,
                                               float* __restrict__ out) {
    extern __shared__ _Float16 smem[];   // 2 bufs x (A 16384h + B 16384h); +rdI
    float* rdI = (float*)(smem + 65536); // 256 floats at byte 131072
    const int tid = threadIdx.x;
    const int lane = tid & 63, w = tid >> 6;  // 8 waves
    const int wr = w >> 2, wcol = w & 3;      // 2M x 4N wave grid
    const int m_ = lane & 15, quad = lane >> 4;

    // XCD pinning: 256 blocks; b = (slot>>4)*8 + xcd; 16 tiles/batch.
    const int bx = blockIdx.x;
    const int xcd = bx & 7, slot = bx >> 3;        // slot 0..31
    const int b  = (slot >> 4) * 8 + xcd;          // 2 batches/XCD
    const int s2 = slot & 15;                      // 16 tiles/batch
    const int I  = (s2 >> 1) * 256;                // 8 I-tiles
    const int D0 = (s2 & 1) * 256;                 // d-pairs adjacent

    const _Float16* Ab = W  + ((size_t)b * NN + I) * NN;
    const _Float16* Bb = vT + ((size_t)b * DD + D0) * NN;

    // Staging geometry: thread t covers row srow = t>>3 (0..63) of a 64-row
    // segment, 16B slot t&7, source col pre-swizzled by (srow&7) so linear
    // LDS dest + swizzled read stay consistent (both-sides rule).
    const int srow = tid >> 3;
    const int scol = ((tid & 7) ^ (srow & 7)) * 8;
    const _Float16* aglb = Ab + (size_t)srow * NN + scol;
    const _Float16* bglb = Bb + (size_t)srow * NN + scol;

    f32x4 acc[8][4];
    #pragma unroll
    for (int i = 0; i < 8; ++i)
        #pragma unroll
        for (int j = 0; j < 4; ++j) acc[i][j] = (f32x4){0.f, 0.f, 0.f, 0.f};

// Stage load l (op=l&1: A/B, seg=l>>1: 64-row group) of tile t_.
#define STG(t_, l_)                                                            \
    async_ld16(&smem[((t_) & 1) * 32768 + ((l_) & 1) * 16384 +                 \
                     ((l_) >> 1) * 4096 + w * 512],                            \
               ((l_) & 1 ? bglb : aglb) + (size_t)((l_) >> 1) * 64 * NN +      \
                   (t_) * 64)

// Load A-frag pair (kc 0,1) for per-wave row-tile i8_ (0..7) from buf cur.
#define PV_LDA(dst_, i8_) do {                                                 \
    const int Ra = wr * 128 + (i8_) * 16 + m_;                                 \
    _Pragma("unroll")                                                          \
    for (int kc = 0; kc < 2; ++kc)                                             \
        dst_[kc] = *(const f16x8*)&smem[cur * 32768 + Ra * 64 +                \
                                        (((kc * 4 + quad) ^ (Ra & 7)) * 8)];   \
    } while (0)

#define PV_MFMA(q_, A0_, A1_) do {                                             \
    __builtin_amdgcn_s_setprio(1);                                             \
    _Pragma("unroll")                                                          \
    for (int jt = 0; jt < 4; ++jt)                                             \
        _Pragma("unroll")                                                      \
        for (int kc = 0; kc < 2; ++kc) {                                       \
            acc[(q_)*2+0][jt] = __builtin_amdgcn_mfma_f32_16x16x32_f16(        \
                A0_[kc], bf[jt][kc], acc[(q_)*2+0][jt], 0, 0, 0);              \
            acc[(q_)*2+1][jt] = __builtin_amdgcn_mfma_f32_16x16x32_f16(        \
                A1_[kc], bf[jt][kc], acc[(q_)*2+1][jt], 0, 0, 0);              \
        }                                                                      \
    __builtin_amdgcn_s_setprio(0);                                             \
    } while (0)

    // Prologue: tiles 0 and 1 fully staged (8 loads each; 16 in flight).
    #pragma unroll
    for (int l = 0; l < 8; ++l) STG(0, l);
    #pragma unroll
    for (int l = 0; l < 8; ++l) STG(1, l);

    const int NT = NN / 64;   // 32 K-tiles
    for (int tc = 0; tc < NT; ++tc) {
        const int cur = tc & 1;
        if (tc == NT - 1) { VM_WAIT(0); } else { VM_WAIT(8); }
        RAW_BAR();            // buf cur complete for all waves
        f16x8 bf[4][2], afA[2][2], afB[2][2];
        // ---- q0: B-frags (whole tile) + A-frags rows 0,1
        #pragma unroll
        for (int jt = 0; jt < 4; ++jt) {
            const int Rb = wcol * 64 + jt * 16 + m_;
            #pragma unroll
            for (int kc = 0; kc < 2; ++kc)
                bf[jt][kc] = *(const f16x8*)&smem[cur * 32768 + 16384 + Rb * 64 +
                                                  (((kc * 4 + quad) ^ (Rb & 7)) * 8)];
        }
        PV_LDA(afA[0], 0); PV_LDA(afA[1], 1);
        RAW_BAR();
        LGKM0_FENCE();
        PV_MFMA(0, afA[0], afA[1]);
        RAW_BAR();
        // ---- q1: A-frags rows 2,3
        PV_LDA(afB[0], 2); PV_LDA(afB[1], 3);
        RAW_BAR();
        LGKM0_FENCE();
        PV_MFMA(1, afB[0], afB[1]);
        RAW_BAR();
        // ---- q2: A-frags rows 4,5 AND prefetch rows 6,7 (q3 becomes read-free)
        PV_LDA(afA[0], 4); PV_LDA(afA[1], 5);
        PV_LDA(afB[0], 6); PV_LDA(afB[1], 7);
        RAW_BAR();
        LGKM0_FENCE();
        PV_MFMA(2, afA[0], afA[1]);
        RAW_BAR();
        // ---- q3: no LDS reads. All waves' cur-reads retired at q2's post-bar
        // -> burst-stage tile t+2 into buf cur (its next user) race-free.
        if (tc + 2 < NT) {
            #pragma unroll
            for (int l = 0; l < 8; ++l) STG(tc + 2, l);
        }
        RAW_BAR();
        PV_MFMA(3, afB[0], afB[1]);
        RAW_BAR();
    }

    // Epilogue: per-row reciprocal denominators via LDS broadcast, NT stores.
    if (tid < 256) rdI[tid] = 1.0f / denom[b * NN + I + tid];
    LGKM_BAR();

    #pragma unroll
    for (int i = 0; i < 8; ++i) {
        const int rowb = wr * 128 + i * 16 + quad * 4;
        #pragma unroll
        for (int r = 0; r < 4; ++r) {
            const float sc = rdI[rowb + r];
            float* op = out + ((size_t)(b * NN + I + rowb + r)) * DD + D0;
            #pragma unroll
            for (int j = 0; j < 4; ++j)
                __builtin_nontemporal_store(acc[i][j][r] * sc,
                                            op + wcol * 64 + j * 16 + m_);
        }
    }
#undef STG
#undef PV_LDA
#undef PV_MFMA
}

// ---------------------------------------------------------------------------
extern "C" void kernel_launch(void* const* d_in, const int* in_sizes, int n_in,
                              void* d_out, int out_size, void* d_ws, size_t ws_size,
                              hipStream_t stream) {
    const float* x = (const float*)d_in[0];
    char* ws = (char*)d_ws;
    _Float16* xhn   = (_Float16*)(ws);                        // 32 MiB normalized fp16
    _Float16* vT    = (_Float16*)(ws + (size_t)33554432);     // 32 MiB fp16 x^T
    _Float16* W     = (_Float16*)(ws + (size_t)67108864);     // 128 MiB fp16 exp-scores
    float*    denom = (float*)   (ws + (size_t)201326592);    // 128 KiB
    float*    out   = (float*)d_out;

    k_prep<<<dim3(NN / 64, BB), 256, 0, stream>>>(x, xhn, vT, denom);
    const int npairs = (NN / 128) * (NN / 128 + 1) / 2;   // 136
    k_scores<<<dim3(npairs, 1, BB), 256, 0, stream>>>(xhn, W, denom);
    // 256 blocks = 1/CU, 8-phase ring-2; 128 KiB bufs + 1 KiB rdI dynamic
    k_pv<<<dim3(256, 1, 1), 512, 132096, stream>>>(W, vT, denom, out);
}

// Round 13
// 172.686 us; speedup vs baseline: 1.0757x; 1.0757x over previous
//
#include <hip/hip_runtime.h>
#include <hip/hip_bf16.h>
#include <cstdint>
#include <cstddef>

// Problem shape (fixed): x [B=16][N=2048][D=512] fp32
#define BB 16
#define NN 2048
#define DD 512

typedef _Float16 f16x8 __attribute__((ext_vector_type(8)));
typedef _Float16 f16x4 __attribute__((ext_vector_type(4)));
typedef float f32x4 __attribute__((ext_vector_type(4)));
typedef unsigned int u32x4 __attribute__((ext_vector_type(4)));

// Async global->LDS, 16 B per lane. LDS dest = wave-uniform base + lane*16.
__device__ __forceinline__ void async_ld16(void* lds, const void* g) {
    __builtin_amdgcn_global_load_lds(
        (const __attribute__((address_space(1))) unsigned int*)(uintptr_t)g,
        (__attribute__((address_space(3))) unsigned int*)(uint32_t)(uintptr_t)lds,
        16, 0, 0);
}

#define VM_WAIT(n) asm volatile("s_waitcnt vmcnt(" #n ")" ::: "memory")
#define RAW_BAR()  do { asm volatile("" ::: "memory"); __builtin_amdgcn_s_barrier(); asm volatile("" ::: "memory"); } while (0)
// LDS-order-only barrier: global stores/atomics keep draining.
#define LGKM_BAR() do { asm volatile("s_waitcnt lgkmcnt(0)" ::: "memory"); \
                        __builtin_amdgcn_s_barrier();                      \
                        __builtin_amdgcn_sched_barrier(0); } while (0)

// ---------------------------------------------------------------------------
// K1 (fused): read x ONCE (non-temporal: stream-once). Per 64-row slab:
// norms, xhn (normalized fp16), vT (fp16 transpose), denom zero-init.
// grid (NN/64, BB), 256 threads.
// ---------------------------------------------------------------------------
__global__ __launch_bounds__(256) void k_prep(const float* __restrict__ x,
                                              _Float16* __restrict__ xhn,
                                              _Float16* __restrict__ vT,
                                              float* __restrict__ denom) {
    __shared__ _Float16 t[512 * 66];     // [d][j], pitch 66 halves
    const int tid = threadIdx.x, lane = tid & 63, w = tid >> 6;
    const int b = blockIdx.y, j0 = blockIdx.x * 64;
    if (tid < 64) denom[b * NN + j0 + tid] = 0.f;
    const float* xb = x + ((size_t)b * NN + j0) * DD;

    for (int rr = 0; rr < 16; ++rr) {
        const int jj = w * 16 + rr;                 // row within slab
        const float* xr = xb + (size_t)jj * DD;
        f32x4 a = __builtin_nontemporal_load((const f32x4*)xr + lane);
        f32x4 c = __builtin_nontemporal_load((const f32x4*)xr + lane + 64);
        float ss = a[0]*a[0] + a[1]*a[1] + a[2]*a[2] + a[3]*a[3]
                 + c[0]*c[0] + c[1]*c[1] + c[2]*c[2] + c[3]*c[3];
        #pragma unroll
        for (int o = 1; o < 64; o <<= 1) ss += __shfl_xor(ss, o);
        const float rn = 1.0f / sqrtf(ss);
        // normalized fp16 row (coalesced 8B stores)
        _Float16* dst = xhn + ((size_t)b * NN + j0 + jj) * DD;
        f16x4 v0 = {(_Float16)(a[0]*rn), (_Float16)(a[1]*rn), (_Float16)(a[2]*rn), (_Float16)(a[3]*rn)};
        f16x4 v1 = {(_Float16)(c[0]*rn), (_Float16)(c[1]*rn), (_Float16)(c[2]*rn), (_Float16)(c[3]*rn)};
        *(f16x4*)(dst + 4 * lane) = v0;
        *(f16x4*)(dst + 256 + 4 * lane) = v1;
        // unnormalized fp16 into transposed LDS tile
        const int d0 = 4 * lane, d1 = 256 + 4 * lane;
        t[(d0 + 0) * 66 + jj] = (_Float16)a[0];
        t[(d0 + 1) * 66 + jj] = (_Float16)a[1];
        t[(d0 + 2) * 66 + jj] = (_Float16)a[2];
        t[(d0 + 3) * 66 + jj] = (_Float16)a[3];
        t[(d1 + 0) * 66 + jj] = (_Float16)c[0];
        t[(d1 + 1) * 66 + jj] = (_Float16)c[1];
        t[(d1 + 2) * 66 + jj] = (_Float16)c[2];
        t[(d1 + 3) * 66 + jj] = (_Float16)c[3];
    }
    LGKM_BAR();   // xhn global stores keep draining under the vT phase
    // store vT rows: 512 d x 8 chunks of 8 halves; 4B-aligned b32 LDS reads.
    #pragma unroll
    for (int it = 0; it < 16; ++it) {
        const int id = it * 256 + tid;
        const int d = id >> 3, ch = (id & 7) * 8;
        const uint32_t* tp = (const uint32_t*)&t[d * 66 + ch];
        uint4 v = {tp[0], tp[1], tp[2], tp[3]};
        *(uint4*)(vT + ((size_t)b * DD + d) * NN + j0 + ch) = v;
    }
}

// ---------------------------------------------------------------------------
// K2: W = exp( xhn xhn^T ), symmetric-triangular. 128x128 block, 4 waves,
// single-buffered BK=64, 34 KiB LDS -> 4 blocks/CU (VGPR-capped max),
// XCD tile-pair swizzle, lane-coalesced 256B-segment stores.
// NEW this round: epilogue reordered — phase-1 W(J,I) stores issue BEFORE
// the denom butterflies+atomics (independent), so the atomic/reduce work
// executes while the 71 MB store stream drains (LGKM-only barriers keep
// stores in flight).
// ---------------------------------------------------------------------------
__global__ __launch_bounds__(256, 4) void k_scores(const _Float16* __restrict__ xhn,
                                                   _Float16* __restrict__ W,
                                                   float* __restrict__ denom) {
    __shared__ _Float16 smem[17408];          // As[8192]+Bs[8192]; epi: 128x136
    const int tid = threadIdx.x;
    const int lane = tid & 63, wv = tid >> 6;
    const int wr = wv >> 1, wc = wv & 1;
    const int m_ = lane & 15, quad = lane >> 4;
    const int b = blockIdx.z;

    // XCD swizzle: 136 = 8 * 17 -> each XCD gets 17 consecutive pairs.
    const int swz = (blockIdx.x % 8) * 17 + blockIdx.x / 8;
    int rem = swz, ti = 0, rowlen = NN / 128;
    while (rem >= rowlen) { rem -= rowlen; ++ti; --rowlen; }
    const int tj = ti + rem;
    const int I = ti * 128, J = tj * 128;
    const bool diag = (ti == tj);

    const _Float16* Ab = xhn + ((size_t)b * NN + I) * DD;
    const _Float16* Bb = xhn + ((size_t)b * NN + J) * DD;

    f32x4 acc[4][4];
    #pragma unroll
    for (int i = 0; i < 4; ++i)
        #pragma unroll
        for (int j = 0; j < 4; ++j) acc[i][j] = (f32x4){0.f, 0.f, 0.f, 0.f};

    const int sub = lane >> 3;
    const int swc = (lane & 7) ^ sub;
    const _Float16* agl = Ab + (size_t)(wv * 32 + sub) * DD + swc * 8;
    const _Float16* bgl = Bb + (size_t)(wv * 32 + sub) * DD + swc * 8;
    _Float16* As = smem;
    _Float16* Bs = smem + 8192;

    for (int kb = 0; kb < DD / 64; ++kb) {
        const int k0 = kb * 64;
        #pragma unroll
        for (int c = 0; c < 4; ++c) {
            async_ld16(&As[(wv * 32 + c * 8) * 64], agl + (size_t)c * 8 * DD + k0);
            async_ld16(&Bs[(wv * 32 + c * 8) * 64], bgl + (size_t)c * 8 * DD + k0);
        }
        VM_WAIT(0);
        RAW_BAR();
        __builtin_amdgcn_s_setprio(1);
        #pragma unroll
        for (int kc = 0; kc < 2; ++kc) {
            f16x8 af[4], bf[4];
            #pragma unroll
            for (int t = 0; t < 4; ++t) {
                const int Ra = wr * 64 + t * 16 + m_;
                const int Rb = wc * 64 + t * 16 + m_;
                af[t] = *(const f16x8*)&As[Ra * 64 + (((kc * 4 + quad) ^ (Ra & 7)) * 8)];
                bf[t] = *(const f16x8*)&Bs[Rb * 64 + (((kc * 4 + quad) ^ (Rb & 7)) * 8)];
            }
            #pragma unroll
            for (int i = 0; i < 4; ++i)
                #pragma unroll
                for (int j = 0; j < 4; ++j)
                    acc[i][j] = __builtin_amdgcn_mfma_f32_16x16x32_f16(af[i], bf[j], acc[i][j], 0, 0, 0);
        }
        __builtin_amdgcn_s_setprio(0);
        RAW_BAR();   // all waves done reading before next stage overwrites
    }

    // Epilogue: exp into packed f16x4; register row/col partial sums.
    f16x4 wq[4][4];
    float rowpart[4][4];
    float colpart[4] = {0.f, 0.f, 0.f, 0.f};
    #pragma unroll
    for (int i = 0; i < 4; ++i)
        #pragma unroll
        for (int r = 0; r < 4; ++r) rowpart[i][r] = 0.f;

    #pragma unroll
    for (int i = 0; i < 4; ++i) {
        #pragma unroll
        for (int j = 0; j < 4; ++j) {
            #pragma unroll
            for (int r = 0; r < 4; ++r) {
                const float w = __expf(acc[i][j][r]);
                wq[i][j][r] = (_Float16)w;
                rowpart[i][r] += w;
                colpart[j] += w;
            }
        }
    }

    // Phase 1 FIRST: WtT[col][row] (stride 136) -> coalesced W(J,I) stores.
    // (K-loop's final RAW_BAR already synced all LDS reads.)
    _Float16* WtT = smem;
    #pragma unroll
    for (int i = 0; i < 4; ++i) {
        const int rowb = wr * 64 + i * 16 + quad * 4;
        #pragma unroll
        for (int j = 0; j < 4; ++j) {
            const int col = wc * 64 + j * 16 + m_;
            *(f16x4*)&WtT[col * 136 + rowb] = wq[i][j];
        }
    }
    LGKM_BAR();
    // lane-coalesced store: 16 lanes = one contiguous 256 B row segment.
    #pragma unroll
    for (int it2 = 0; it2 < 8; ++it2) {
        const int id = it2 * 256 + tid;
        const int rr = id >> 4, off = (id & 15) * 8;
        *(uint4*)(W + ((size_t)b * NN + J + rr) * NN + I + off) =
            *(const uint4*)&WtT[rr * 136 + off];
    }

    // Denom butterflies + atomics WHILE the W(J,I) store stream drains.
    #pragma unroll
    for (int i = 0; i < 4; ++i) {
        #pragma unroll
        for (int r = 0; r < 4; ++r) {
            float s = rowpart[i][r];
            s += __shfl_xor(s, 1);
            s += __shfl_xor(s, 2);
            s += __shfl_xor(s, 4);
            s += __shfl_xor(s, 8);
            if (m_ == 0)
                atomicAdd(&denom[b * NN + I + wr * 64 + i * 16 + quad * 4 + r], s);
        }
    }
    if (!diag) {
        #pragma unroll
        for (int j = 0; j < 4; ++j) {
            float s = colpart[j];
            s += __shfl_xor(s, 16);
            s += __shfl_xor(s, 32);
            if (quad == 0)
                atomicAdd(&denom[b * NN + J + wc * 64 + j * 16 + m_], s);
        }
    }

    // Phase 2 (off-diag): row-major Wt -> coalesced W(I,J).
    if (!diag) {
        LGKM_BAR();   // phase-1 LDS reads done; stores/atomics still in flight
        _Float16* Wt = smem;
        #pragma unroll
        for (int i = 0; i < 4; ++i) {
            const int rowb = wr * 64 + i * 16 + quad * 4;
            #pragma unroll
            for (int j = 0; j < 4; ++j) {
                const int col = wc * 64 + j * 16 + m_;
                #pragma unroll
                for (int r = 0; r < 4; ++r)
                    Wt[(rowb + r) * 136 + col] = wq[i][j][r];
            }
        }
        LGKM_BAR();
        #pragma unroll
        for (int it2 = 0; it2 < 8; ++it2) {
            const int id = it2 * 256 + tid;
            const int rr = id >> 4, off = (id & 15) * 8;
            *(uint4*)(W + ((size_t)b * NN + I + rr) * NN + J + off) =
                *(const uint4*)&Wt[rr * 136 + off];
        }
    }
}

// ---------------------------------------------------------------------------
// K3 (REVERTED to R11 exact — measured ~75 us; 8-phase/4-phase 1-block
// variants both ~85): O = (W @ V) * (1/denom_i).
// Tile 128(I) x 256(D), 8 waves (2Mx4N, per-wave 64x64), BK=64, SINGLE-
// buffered static LDS 48.5 KiB -> 2 blocks/CU: cross-block TLP hides the
// per-step vmcnt(0) drain (m114). W staging cached (L3-resident); out NT.
// XCD batch-pinning, d-pairs adjacent (W panel L2-shared).
// ---------------------------------------------------------------------------
__global__ __launch_bounds__(512, 4) void k_pv(const _Float16* __restrict__ W,
                                               const _Float16* __restrict__ vT,
                                               const float* __restrict__ denom,
                                               float* __restrict__ out) {
    __shared__ _Float16 smem[24576];   // As[128][64]=8192h, Bs[256][64]=16384h
    __shared__ float rdI[128];
    const int tid = threadIdx.x;
    const int lane = tid & 63, w = tid >> 6;  // 8 waves
    const int wr = w >> 2, wcol = w & 3;      // 2 x 4 wave grid
    const int m_ = lane & 15, quad = lane >> 4;

    // XCD pinning: 512 blocks, 64 slots per XCD, 2 batches per XCD.
    const int bx = blockIdx.x;
    const int xcd = bx & 7, slot = bx >> 3;        // slot 0..63
    const int b  = (slot >> 5) * 8 + xcd;          // 2 batches/XCD
    const int s2 = slot & 31;                      // 32 blocks/batch
    const int I  = (s2 >> 1) * 128;                // 16 I-tiles
    const int D0 = (s2 & 1) * 256;                 // d-pairs adjacent

    const _Float16* Ab = W  + ((size_t)b * NN + I) * NN;
    const _Float16* Bb = vT + ((size_t)b * DD + D0) * NN;

    const int sub = lane >> 3;
    const int swc = (lane & 7) ^ sub;
    // A: 128 rows, wave stages 16 rows (2 chunks of 8).
    const _Float16* agl = Ab + (size_t)(w * 16 + sub) * NN + swc * 8;
    // B: 256 rows, wave stages 32 rows (4 chunks of 8).
    const _Float16* bgl = Bb + (size_t)(w * 32 + sub) * NN + swc * 8;
    _Float16* As = smem;
    _Float16* Bs = smem + 8192;

    f32x4 acc[4][4];
    #pragma unroll
    for (int i = 0; i < 4; ++i)
        #pragma unroll
        for (int j = 0; j < 4; ++j) acc[i][j] = (f32x4){0.f, 0.f, 0.f, 0.f};

    for (int kb = 0; kb < NN / 64; ++kb) {
        const int k0 = kb * 64;
        #pragma unroll
        for (int c = 0; c < 2; ++c)
            async_ld16(&As[(w * 16 + c * 8) * 64], agl + (size_t)c * 8 * NN + k0);
        #pragma unroll
        for (int c = 0; c < 4; ++c)
            async_ld16(&Bs[(w * 32 + c * 8) * 64], bgl + (size_t)c * 8 * NN + k0);
        VM_WAIT(0);
        RAW_BAR();
        __builtin_amdgcn_s_setprio(1);
        #pragma unroll
        for (int kc = 0; kc < 2; ++kc) {
            f16x8 af[4], bf[4];
            #pragma unroll
            for (int t = 0; t < 4; ++t) {
                const int Ra = wr * 64 + t * 16 + m_;
                const int Rb = wcol * 64 + t * 16 + m_;
                af[t] = *(const f16x8*)&As[Ra * 64 + (((kc * 4 + quad) ^ (Ra & 7)) * 8)];
                bf[t] = *(const f16x8*)&Bs[Rb * 64 + (((kc * 4 + quad) ^ (Rb & 7)) * 8)];
            }
            #pragma unroll
            for (int i = 0; i < 4; ++i)
                #pragma unroll
                for (int j = 0; j < 4; ++j)
                    acc[i][j] = __builtin_amdgcn_mfma_f32_16x16x32_f16(af[i], bf[j], acc[i][j], 0, 0, 0);
        }
        __builtin_amdgcn_s_setprio(0);
        RAW_BAR();   // all waves done reading before next stage overwrites
    }

    // Epilogue: per-row reciprocal denominators via LDS broadcast, NT stores.
    if (tid < 128) rdI[tid] = 1.0f / denom[b * NN + I + tid];
    LGKM_BAR();

    #pragma unroll
    for (int i = 0; i < 4; ++i) {
        const int rowb = wr * 64 + i * 16 + quad * 4;
        #pragma unroll
        for (int r = 0; r < 4; ++r) {
            const float sc = rdI[rowb + r];
            float* op = out + ((size_t)(b * NN + I + rowb + r)) * DD + D0;
            #pragma unroll
            for (int j = 0; j < 4; ++j)
                __builtin_nontemporal_store(acc[i][j][r] * sc,
                                            op + wcol * 64 + j * 16 + m_);
        }
    }
}

// ---------------------------------------------------------------------------
extern "C" void kernel_launch(void* const* d_in, const int* in_sizes, int n_in,
                              void* d_out, int out_size, void* d_ws, size_t ws_size,
                              hipStream_t stream) {
    const float* x = (const float*)d_in[0];
    char* ws = (char*)d_ws;
    _Float16* xhn   = (_Float16*)(ws);                        // 32 MiB normalized fp16
    _Float16* vT    = (_Float16*)(ws + (size_t)33554432);     // 32 MiB fp16 x^T
    _Float16* W     = (_Float16*)(ws + (size_t)67108864);     // 128 MiB fp16 exp-scores
    float*    denom = (float*)   (ws + (size_t)201326592);    // 128 KiB
    float*    out   = (float*)d_out;

    k_prep<<<dim3(NN / 64, BB), 256, 0, stream>>>(x, xhn, vT, denom);
    const int npairs = (NN / 128) * (NN / 128 + 1) / 2;   // 136
    k_scores<<<dim3(npairs, 1, BB), 256, 0, stream>>>(xhn, W, denom);
    // 512 blocks = 2 blocks/CU (static 48.5 KiB LDS), XCD batch-pinned
    k_pv<<<dim3(512, 1, 1), 512, 0, stream>>>(W, vT, denom, out);
}

// Round 14
// 171.974 us; speedup vs baseline: 1.0802x; 1.0041x over previous
//
#include <hip/hip_runtime.h>
#include <hip/hip_bf16.h>
#include <cstdint>
#include <cstddef>

// Problem shape (fixed): x [B=16][N=2048][D=512] fp32
#define BB 16
#define NN 2048
#define DD 512

typedef _Float16 f16x8 __attribute__((ext_vector_type(8)));
typedef _Float16 f16x4 __attribute__((ext_vector_type(4)));
typedef float f32x4 __attribute__((ext_vector_type(4)));
typedef unsigned int u32x4 __attribute__((ext_vector_type(4)));

// Async global->LDS, 16 B per lane. LDS dest = wave-uniform base + lane*16.
__device__ __forceinline__ void async_ld16(void* lds, const void* g) {
    __builtin_amdgcn_global_load_lds(
        (const __attribute__((address_space(1))) unsigned int*)(uintptr_t)g,
        (__attribute__((address_space(3))) unsigned int*)(uint32_t)(uintptr_t)lds,
        16, 0, 0);
}

#define VM_WAIT(n) asm volatile("s_waitcnt vmcnt(" #n ")" ::: "memory")
#define RAW_BAR()  do { asm volatile("" ::: "memory"); __builtin_amdgcn_s_barrier(); asm volatile("" ::: "memory"); } while (0)
// LDS-order-only barrier: global stores/atomics keep draining.
#define LGKM_BAR() do { asm volatile("s_waitcnt lgkmcnt(0)" ::: "memory"); \
                        __builtin_amdgcn_s_barrier();                      \
                        __builtin_amdgcn_sched_barrier(0); } while (0)

// ---------------------------------------------------------------------------
// K1 (fused): read x ONCE (non-temporal: stream-once). Per 64-row slab:
// norms, xhn (normalized fp16), vT (fp16 transpose), denom zero-init.
// grid (NN/64, BB), 256 threads.
// ---------------------------------------------------------------------------
__global__ __launch_bounds__(256) void k_prep(const float* __restrict__ x,
                                              _Float16* __restrict__ xhn,
                                              _Float16* __restrict__ vT,
                                              float* __restrict__ denom) {
    __shared__ _Float16 t[512 * 66];     // [d][j], pitch 66 halves
    const int tid = threadIdx.x, lane = tid & 63, w = tid >> 6;
    const int b = blockIdx.y, j0 = blockIdx.x * 64;
    if (tid < 64) denom[b * NN + j0 + tid] = 0.f;
    const float* xb = x + ((size_t)b * NN + j0) * DD;

    for (int rr = 0; rr < 16; ++rr) {
        const int jj = w * 16 + rr;                 // row within slab
        const float* xr = xb + (size_t)jj * DD;
        f32x4 a = __builtin_nontemporal_load((const f32x4*)xr + lane);
        f32x4 c = __builtin_nontemporal_load((const f32x4*)xr + lane + 64);
        float ss = a[0]*a[0] + a[1]*a[1] + a[2]*a[2] + a[3]*a[3]
                 + c[0]*c[0] + c[1]*c[1] + c[2]*c[2] + c[3]*c[3];
        #pragma unroll
        for (int o = 1; o < 64; o <<= 1) ss += __shfl_xor(ss, o);
        const float rn = 1.0f / sqrtf(ss);
        // normalized fp16 row (coalesced 8B stores)
        _Float16* dst = xhn + ((size_t)b * NN + j0 + jj) * DD;
        f16x4 v0 = {(_Float16)(a[0]*rn), (_Float16)(a[1]*rn), (_Float16)(a[2]*rn), (_Float16)(a[3]*rn)};
        f16x4 v1 = {(_Float16)(c[0]*rn), (_Float16)(c[1]*rn), (_Float16)(c[2]*rn), (_Float16)(c[3]*rn)};
        *(f16x4*)(dst + 4 * lane) = v0;
        *(f16x4*)(dst + 256 + 4 * lane) = v1;
        // unnormalized fp16 into transposed LDS tile
        const int d0 = 4 * lane, d1 = 256 + 4 * lane;
        t[(d0 + 0) * 66 + jj] = (_Float16)a[0];
        t[(d0 + 1) * 66 + jj] = (_Float16)a[1];
        t[(d0 + 2) * 66 + jj] = (_Float16)a[2];
        t[(d0 + 3) * 66 + jj] = (_Float16)a[3];
        t[(d1 + 0) * 66 + jj] = (_Float16)c[0];
        t[(d1 + 1) * 66 + jj] = (_Float16)c[1];
        t[(d1 + 2) * 66 + jj] = (_Float16)c[2];
        t[(d1 + 3) * 66 + jj] = (_Float16)c[3];
    }
    LGKM_BAR();   // xhn global stores keep draining under the vT phase
    // store vT rows: 512 d x 8 chunks of 8 halves; 4B-aligned b32 LDS reads.
    #pragma unroll
    for (int it = 0; it < 16; ++it) {
        const int id = it * 256 + tid;
        const int d = id >> 3, ch = (id & 7) * 8;
        const uint32_t* tp = (const uint32_t*)&t[d * 66 + ch];
        uint4 v = {tp[0], tp[1], tp[2], tp[3]};
        *(uint4*)(vT + ((size_t)b * DD + d) * NN + j0 + ch) = v;
    }
}

// ---------------------------------------------------------------------------
// K2 (unchanged from R13): W = exp( xhn xhn^T ), symmetric-triangular.
// 128x128 block, 4 waves, single-buffered BK=64, 34 KiB LDS -> 4 blocks/CU,
// XCD tile-pair swizzle, lane-coalesced 256B-segment stores, stores-before-
// atomics epilogue ordering, LGKM-only barriers.
// ---------------------------------------------------------------------------
__global__ __launch_bounds__(256, 4) void k_scores(const _Float16* __restrict__ xhn,
                                                   _Float16* __restrict__ W,
                                                   float* __restrict__ denom) {
    __shared__ _Float16 smem[17408];          // As[8192]+Bs[8192]; epi: 128x136
    const int tid = threadIdx.x;
    const int lane = tid & 63, wv = tid >> 6;
    const int wr = wv >> 1, wc = wv & 1;
    const int m_ = lane & 15, quad = lane >> 4;
    const int b = blockIdx.z;

    // XCD swizzle: 136 = 8 * 17 -> each XCD gets 17 consecutive pairs.
    const int swz = (blockIdx.x % 8) * 17 + blockIdx.x / 8;
    int rem = swz, ti = 0, rowlen = NN / 128;
    while (rem >= rowlen) { rem -= rowlen; ++ti; --rowlen; }
    const int tj = ti + rem;
    const int I = ti * 128, J = tj * 128;
    const bool diag = (ti == tj);

    const _Float16* Ab = xhn + ((size_t)b * NN + I) * DD;
    const _Float16* Bb = xhn + ((size_t)b * NN + J) * DD;

    f32x4 acc[4][4];
    #pragma unroll
    for (int i = 0; i < 4; ++i)
        #pragma unroll
        for (int j = 0; j < 4; ++j) acc[i][j] = (f32x4){0.f, 0.f, 0.f, 0.f};

    const int sub = lane >> 3;
    const int swc = (lane & 7) ^ sub;
    const _Float16* agl = Ab + (size_t)(wv * 32 + sub) * DD + swc * 8;
    const _Float16* bgl = Bb + (size_t)(wv * 32 + sub) * DD + swc * 8;
    _Float16* As = smem;
    _Float16* Bs = smem + 8192;

    for (int kb = 0; kb < DD / 64; ++kb) {
        const int k0 = kb * 64;
        #pragma unroll
        for (int c = 0; c < 4; ++c) {
            async_ld16(&As[(wv * 32 + c * 8) * 64], agl + (size_t)c * 8 * DD + k0);
            async_ld16(&Bs[(wv * 32 + c * 8) * 64], bgl + (size_t)c * 8 * DD + k0);
        }
        VM_WAIT(0);
        RAW_BAR();
        __builtin_amdgcn_s_setprio(1);
        #pragma unroll
        for (int kc = 0; kc < 2; ++kc) {
            f16x8 af[4], bf[4];
            #pragma unroll
            for (int t = 0; t < 4; ++t) {
                const int Ra = wr * 64 + t * 16 + m_;
                const int Rb = wc * 64 + t * 16 + m_;
                af[t] = *(const f16x8*)&As[Ra * 64 + (((kc * 4 + quad) ^ (Ra & 7)) * 8)];
                bf[t] = *(const f16x8*)&Bs[Rb * 64 + (((kc * 4 + quad) ^ (Rb & 7)) * 8)];
            }
            #pragma unroll
            for (int i = 0; i < 4; ++i)
                #pragma unroll
                for (int j = 0; j < 4; ++j)
                    acc[i][j] = __builtin_amdgcn_mfma_f32_16x16x32_f16(af[i], bf[j], acc[i][j], 0, 0, 0);
        }
        __builtin_amdgcn_s_setprio(0);
        RAW_BAR();   // all waves done reading before next stage overwrites
    }

    // Epilogue: exp into packed f16x4; register row/col partial sums.
    f16x4 wq[4][4];
    float rowpart[4][4];
    float colpart[4] = {0.f, 0.f, 0.f, 0.f};
    #pragma unroll
    for (int i = 0; i < 4; ++i)
        #pragma unroll
        for (int r = 0; r < 4; ++r) rowpart[i][r] = 0.f;

    #pragma unroll
    for (int i = 0; i < 4; ++i) {
        #pragma unroll
        for (int j = 0; j < 4; ++j) {
            #pragma unroll
            for (int r = 0; r < 4; ++r) {
                const float w = __expf(acc[i][j][r]);
                wq[i][j][r] = (_Float16)w;
                rowpart[i][r] += w;
                colpart[j] += w;
            }
        }
    }

    // Phase 1 FIRST: WtT[col][row] (stride 136) -> coalesced W(J,I) stores.
    _Float16* WtT = smem;
    #pragma unroll
    for (int i = 0; i < 4; ++i) {
        const int rowb = wr * 64 + i * 16 + quad * 4;
        #pragma unroll
        for (int j = 0; j < 4; ++j) {
            const int col = wc * 64 + j * 16 + m_;
            *(f16x4*)&WtT[col * 136 + rowb] = wq[i][j];
        }
    }
    LGKM_BAR();
    // lane-coalesced store: 16 lanes = one contiguous 256 B row segment.
    #pragma unroll
    for (int it2 = 0; it2 < 8; ++it2) {
        const int id = it2 * 256 + tid;
        const int rr = id >> 4, off = (id & 15) * 8;
        *(uint4*)(W + ((size_t)b * NN + J + rr) * NN + I + off) =
            *(const uint4*)&WtT[rr * 136 + off];
    }

    // Denom butterflies + atomics WHILE the W(J,I) store stream drains.
    #pragma unroll
    for (int i = 0; i < 4; ++i) {
        #pragma unroll
        for (int r = 0; r < 4; ++r) {
            float s = rowpart[i][r];
            s += __shfl_xor(s, 1);
            s += __shfl_xor(s, 2);
            s += __shfl_xor(s, 4);
            s += __shfl_xor(s, 8);
            if (m_ == 0)
                atomicAdd(&denom[b * NN + I + wr * 64 + i * 16 + quad * 4 + r], s);
        }
    }
    if (!diag) {
        #pragma unroll
        for (int j = 0; j < 4; ++j) {
            float s = colpart[j];
            s += __shfl_xor(s, 16);
            s += __shfl_xor(s, 32);
            if (quad == 0)
                atomicAdd(&denom[b * NN + J + wc * 64 + j * 16 + m_], s);
        }
    }

    // Phase 2 (off-diag): row-major Wt -> coalesced W(I,J).
    if (!diag) {
        LGKM_BAR();   // phase-1 LDS reads done; stores/atomics still in flight
        _Float16* Wt = smem;
        #pragma unroll
        for (int i = 0; i < 4; ++i) {
            const int rowb = wr * 64 + i * 16 + quad * 4;
            #pragma unroll
            for (int j = 0; j < 4; ++j) {
                const int col = wc * 64 + j * 16 + m_;
                #pragma unroll
                for (int r = 0; r < 4; ++r)
                    Wt[(rowb + r) * 136 + col] = wq[i][j][r];
            }
        }
        LGKM_BAR();
        #pragma unroll
        for (int it2 = 0; it2 < 8; ++it2) {
            const int id = it2 * 256 + tid;
            const int rr = id >> 4, off = (id & 15) * 8;
            *(uint4*)(W + ((size_t)b * NN + I + rr) * NN + J + off) =
                *(const uint4*)&Wt[rr * 136 + off];
        }
    }
}

// ---------------------------------------------------------------------------
// K3: O = (W @ V) * (1/denom_i), fp32 out.
// NEW: finer block granularity at the SAME 16 waves/CU — 128x128 tile,
// 4-wave blocks (2Mx2N, per-wave 64x64), single-buffer 32.5 KiB LDS ->
// 4 blocks/CU (was 2x8-wave), grid 1024 = exactly 4 rounds, zero tail.
// More independent blocks at same occupancy = more phase-desync for the
// cross-block TLP that hides the per-step vmcnt(0) drain (R7's proven
// transformation applied to k_pv). 4 D-blocks of one W row-panel now sit
// on ADJACENT slots of the same XCD (panel L2-shared 4x, was 2x).
// W staging cached (L3-resident); out stores NT; XCD batch-pinned.
// ---------------------------------------------------------------------------
__global__ __launch_bounds__(256, 4) void k_pv(const _Float16* __restrict__ W,
                                               const _Float16* __restrict__ vT,
                                               const float* __restrict__ denom,
                                               float* __restrict__ out) {
    __shared__ _Float16 As[8192];      // [128][64]
    __shared__ _Float16 Bs[8192];      // [128][64]
    __shared__ float rdI[128];
    const int tid = threadIdx.x;
    const int lane = tid & 63, w = tid >> 6;  // 4 waves
    const int wr = w >> 1, wc = w & 1;        // 2 x 2 wave grid
    const int m_ = lane & 15, quad = lane >> 4;

    // XCD pinning: 1024 blocks, 128 slots/XCD, 2 batches/XCD.
    const int bx = blockIdx.x;
    const int xcd = bx & 7, slot = bx >> 3;        // slot 0..127
    const int b  = (slot >> 6) * 8 + xcd;          // 2 batches/XCD
    const int r_ = slot & 63;                      // 64 blocks/batch
    const int I  = (r_ >> 2) * 128;                // 16 I-tiles
    const int D0 = (r_ & 3) * 128;                 // 4 D-blocks adjacent

    const _Float16* Ab = W  + ((size_t)b * NN + I) * NN;
    const _Float16* Bb = vT + ((size_t)b * DD + D0) * NN;

    const int sub = lane >> 3;
    const int swc = (lane & 7) ^ sub;
    // A: 128 rows, wave stages 32 rows (4 chunks of 8). B: same.
    const _Float16* agl = Ab + (size_t)(w * 32 + sub) * NN + swc * 8;
    const _Float16* bgl = Bb + (size_t)(w * 32 + sub) * NN + swc * 8;

    f32x4 acc[4][4];
    #pragma unroll
    for (int i = 0; i < 4; ++i)
        #pragma unroll
        for (int j = 0; j < 4; ++j) acc[i][j] = (f32x4){0.f, 0.f, 0.f, 0.f};

    for (int kb = 0; kb < NN / 64; ++kb) {
        const int k0 = kb * 64;
        #pragma unroll
        for (int c = 0; c < 4; ++c) {
            async_ld16(&As[(w * 32 + c * 8) * 64], agl + (size_t)c * 8 * NN + k0);
            async_ld16(&Bs[(w * 32 + c * 8) * 64], bgl + (size_t)c * 8 * NN + k0);
        }
        VM_WAIT(0);
        RAW_BAR();
        __builtin_amdgcn_s_setprio(1);
        #pragma unroll
        for (int kc = 0; kc < 2; ++kc) {
            f16x8 af[4], bf[4];
            #pragma unroll
            for (int t = 0; t < 4; ++t) {
                const int Ra = wr * 64 + t * 16 + m_;
                const int Rb = wc * 64 + t * 16 + m_;
                af[t] = *(const f16x8*)&As[Ra * 64 + (((kc * 4 + quad) ^ (Ra & 7)) * 8)];
                bf[t] = *(const f16x8*)&Bs[Rb * 64 + (((kc * 4 + quad) ^ (Rb & 7)) * 8)];
            }
            #pragma unroll
            for (int i = 0; i < 4; ++i)
                #pragma unroll
                for (int j = 0; j < 4; ++j)
                    acc[i][j] = __builtin_amdgcn_mfma_f32_16x16x32_f16(af[i], bf[j], acc[i][j], 0, 0, 0);
        }
        __builtin_amdgcn_s_setprio(0);
        RAW_BAR();   // all waves done reading before next stage overwrites
    }

    // Epilogue: per-row reciprocal denominators via LDS broadcast, NT stores.
    if (tid < 128) rdI[tid] = 1.0f / denom[b * NN + I + tid];
    LGKM_BAR();

    #pragma unroll
    for (int i = 0; i < 4; ++i) {
        const int rowb = wr * 64 + i * 16 + quad * 4;
        #pragma unroll
        for (int r = 0; r < 4; ++r) {
            const float sc = rdI[rowb + r];
            float* op = out + ((size_t)(b * NN + I + rowb + r)) * DD + D0;
            #pragma unroll
            for (int j = 0; j < 4; ++j)
                __builtin_nontemporal_store(acc[i][j][r] * sc,
                                            op + wc * 64 + j * 16 + m_);
        }
    }
}

// ---------------------------------------------------------------------------
extern "C" void kernel_launch(void* const* d_in, const int* in_sizes, int n_in,
                              void* d_out, int out_size, void* d_ws, size_t ws_size,
                              hipStream_t stream) {
    const float* x = (const float*)d_in[0];
    char* ws = (char*)d_ws;
    _Float16* xhn   = (_Float16*)(ws);                        // 32 MiB normalized fp16
    _Float16* vT    = (_Float16*)(ws + (size_t)33554432);     // 32 MiB fp16 x^T
    _Float16* W     = (_Float16*)(ws + (size_t)67108864);     // 128 MiB fp16 exp-scores
    float*    denom = (float*)   (ws + (size_t)201326592);    // 128 KiB
    float*    out   = (float*)d_out;

    k_prep<<<dim3(NN / 64, BB), 256, 0, stream>>>(x, xhn, vT, denom);
    const int npairs = (NN / 128) * (NN / 128 + 1) / 2;   // 136
    k_scores<<<dim3(npairs, 1, BB), 256, 0, stream>>>(xhn, W, denom);
    // 1024 blocks = 4 blocks/CU (32.5 KiB LDS, 4-wave blocks), XCD batch-pinned
    k_pv<<<dim3(1024, 1, 1), 256, 0, stream>>>(W, vT, denom, out);
}